// Round 2
// baseline (1365.602 us; speedup 1.0000x reference)
//
#include <hip/hip_runtime.h>
#include <hip/hip_bf16.h>

// AutoInt fused kernel, MI355X gfx950.
// Harness: fp32 inputs/outputs (per reference dtypes); bf16-tolerance compare
// (threshold 8x bf16 eps) -> internal compute in bf16 MFMA + fp32 accumulate.
//
// Shapes: x[8192][64][256] f32; Wq/Wk/Wv/W1 [256][256] f32; bq/bk/bv/b1 [256] f32;
//         W2 [16384] f32; b2 [1] f32; out [8192] f32 (sigmoid scalar per row).

#define NFEAT   64
#define DIM     256
#define NHEAD   8
#define DH      32
#define NBATCH  8192

typedef __attribute__((ext_vector_type(8))) short short8;   // 8 bf16 = 4 VGPR (MFMA A/B frag)
typedef __attribute__((ext_vector_type(4))) short short4v;  // 4 bf16 = 8B
typedef __attribute__((ext_vector_type(4))) float floatx4;  // MFMA C/D frag

#define LDA 264   // row stride (elems) for sX/sQ/sK: 256+8 pad
#define LDV 72    // row stride for sVT ([dim][feat]) and sP: 64+8 pad

__device__ __forceinline__ float bf2f(ushort u) {
    union { float f; uint32_t i; } c; c.i = ((uint32_t)u) << 16; return c.f;
}
__device__ __forceinline__ ushort f2bf(float f) {
    union { float f; uint32_t i; } c; c.f = f;
    uint32_t i = c.i;
    return (ushort)((i + 0x7fffu + ((i >> 16) & 1u)) >> 16);  // RNE
}

// Transpose the 4 [256][256] fp32 weight matrices into ws as bf16 WT[n][k] so
// the MFMA B-fragment (lane n fixed, 8 consecutive k) is a contiguous 16B load.
__global__ void transpose4(const float* __restrict__ wq, const float* __restrict__ wk,
                           const float* __restrict__ wv, const float* __restrict__ w1,
                           ushort* __restrict__ ws) {
    const float* src = (blockIdx.y == 0) ? wq : (blockIdx.y == 1) ? wk
                       : (blockIdx.y == 2) ? wv : w1;
    int k = blockIdx.x;       // source row
    int n = threadIdx.x;      // source col (coalesced read)
    ws[(size_t)blockIdx.y * (DIM * DIM) + n * DIM + k] = f2bf(src[k * DIM + n]);
}

__global__ __launch_bounds__(512, 2) void autoint_kernel(
    const float* __restrict__ x,      // [B][64][256] f32
    const ushort* __restrict__ wqT,   // [256][256] bf16, transposed (n,k)
    const ushort* __restrict__ wkT,
    const ushort* __restrict__ wvT,
    const ushort* __restrict__ w1T,
    const float* __restrict__ bq,
    const float* __restrict__ bk,
    const float* __restrict__ bv,
    const float* __restrict__ b1,
    const float* __restrict__ w2,     // [16384] f32
    const float* __restrict__ b2,     // [1] f32
    float* __restrict__ out)          // [B] f32
{
    __shared__ __align__(16) ushort sX[NFEAT * LDA];       // x  (bf16)          33792 B
    __shared__ __align__(16) ushort sQ[NFEAT * LDA];       // Q, then Z per-head 33792 B
    __shared__ __align__(16) ushort sK[NFEAT * LDA];       //                    33792 B
    __shared__ __align__(16) ushort sVT[DIM * LDV];        // V^T [dim][feat]    36864 B
    __shared__ __align__(16) ushort sP[2][NFEAT * LDV];    // softmax P, 2 heads 18432 B
    __shared__ float sRed[8];

    const int tid  = threadIdx.x;
    const int wave = tid >> 6;
    const int lane = tid & 63;
    const int quad = lane >> 4;   // 0..3
    const int lm   = lane & 15;   // 0..15

    // ---- Phase 0: stage x[b] into LDS as bf16 (padded rows) ----
    const float* xb = x + (size_t)blockIdx.x * (NFEAT * DIM);
    #pragma unroll
    for (int i = 0; i < 8; i++) {
        int g   = tid + i * 512;        // 0..4095 group-of-4 index
        int el  = g * 4;                // float index
        int row = el >> 8;
        int col = el & 255;
        float4 v = *(const float4*)(xb + el);
        short4v p;
        p[0] = (short)f2bf(v.x); p[1] = (short)f2bf(v.y);
        p[2] = (short)f2bf(v.z); p[3] = (short)f2bf(v.w);
        *(short4v*)(&sX[row * LDA + col]) = p;
    }
    __syncthreads();

    // ---- Phase 1: projections Q, K, V^T ----
    // Wave w covers n-tiles {2w, 2w+1} (B-frag loaded once, reused over 4 m-tiles).
    const int nbase = wave * 2;
    {
        const ushort* wT[3]  = { wqT, wkT, wvT };
        const float* bias[3] = { bq, bk, bv };
        #pragma unroll
        for (int pj = 0; pj < 3; pj++) {
            floatx4 acc[4][2];
            #pragma unroll
            for (int mt = 0; mt < 4; mt++)
                #pragma unroll
                for (int n = 0; n < 2; n++)
                    acc[mt][n] = (floatx4){0.f, 0.f, 0.f, 0.f};
            for (int k0 = 0; k0 < DIM; k0 += 32) {
                short8 a[4], b[2];
                #pragma unroll
                for (int mt = 0; mt < 4; mt++)
                    a[mt] = *(const short8*)(&sX[(mt * 16 + lm) * LDA + k0 + quad * 8]);
                #pragma unroll
                for (int n = 0; n < 2; n++)
                    b[n] = *(const short8*)(&wT[pj][((nbase + n) * 16 + lm) * DIM + k0 + quad * 8]);
                #pragma unroll
                for (int mt = 0; mt < 4; mt++)
                    #pragma unroll
                    for (int n = 0; n < 2; n++)
                        acc[mt][n] = __builtin_amdgcn_mfma_f32_16x16x32_bf16(
                            a[mt], b[n], acc[mt][n], 0, 0, 0);
            }
            // epilogue: +bias, write Q/K rows or V transposed
            #pragma unroll
            for (int n = 0; n < 2; n++) {
                int ncol = (nbase + n) * 16 + lm;
                float bvs = bias[pj][ncol];
                #pragma unroll
                for (int mt = 0; mt < 4; mt++) {
                    if (pj < 2) {
                        ushort* dst = (pj == 0) ? sQ : sK;
                        #pragma unroll
                        for (int r = 0; r < 4; r++) {
                            int row = mt * 16 + quad * 4 + r;  // C/D: row=(lane>>4)*4+reg
                            dst[row * LDA + ncol] = f2bf(acc[mt][n][r] + bvs);
                        }
                    } else {
                        short4v pk;
                        #pragma unroll
                        for (int r = 0; r < 4; r++)
                            pk[r] = (short)f2bf(acc[mt][n][r] + bvs);
                        // V^T[dim=ncol][feat=mt*16+quad*4 .. +3] contiguous -> 8B store
                        *(short4v*)(&sVT[ncol * LDV + mt * 16 + quad * 4]) = pk;
                    }
                }
            }
        }
    }
    __syncthreads();

    // ---- Phase 2: attention, 2 heads at a time ----
    const int hw = wave >> 2;   // head subgroup (0/1)
    const int wg = wave & 3;    // row-tile within subgroup
    const float scale = 0.1767766952966369f;  // 1/sqrt(32)

    for (int it = 0; it < 4; it++) {
        int h  = it * 2 + hw;
        int hc = h * DH;        // column base of this head in sQ/sK (and sVT rows)

        // S = Q_h K_h^T: wave wg -> rows 16wg..16wg+15, all 4 j-tiles; K=32 in one MFMA
        floatx4 s[4];
        short8 aq = *(const short8*)(&sQ[(wg * 16 + lm) * LDA + hc + quad * 8]);
        #pragma unroll
        for (int jt = 0; jt < 4; jt++) {
            short8 bkf = *(const short8*)(&sK[(jt * 16 + lm) * LDA + hc + quad * 8]);
            floatx4 z4 = (floatx4){0.f, 0.f, 0.f, 0.f};
            s[jt] = __builtin_amdgcn_mfma_f32_16x16x32_bf16(aq, bkf, z4, 0, 0, 0);
        }

        // softmax over j (row lives in the 16 lanes of this quad x 4 jt regs)
        #pragma unroll
        for (int r = 0; r < 4; r++) {
            float p0 = s[0][r] * scale, p1 = s[1][r] * scale,
                  p2 = s[2][r] * scale, p3 = s[3][r] * scale;
            float m = fmaxf(fmaxf(p0, p1), fmaxf(p2, p3));
            #pragma unroll
            for (int off = 1; off < 16; off <<= 1)
                m = fmaxf(m, __shfl_xor(m, off, 64));
            float e0 = __expf(p0 - m), e1 = __expf(p1 - m),
                  e2 = __expf(p2 - m), e3 = __expf(p3 - m);
            float sum = e0 + e1 + e2 + e3;
            #pragma unroll
            for (int off = 1; off < 16; off <<= 1)
                sum += __shfl_xor(sum, off, 64);
            float inv = 1.0f / sum;
            int row = wg * 16 + quad * 4 + r;
            sP[hw][row * LDV +  0 + lm] = f2bf(e0 * inv);
            sP[hw][row * LDV + 16 + lm] = f2bf(e1 * inv);
            sP[hw][row * LDV + 32 + lm] = f2bf(e2 * inv);
            sP[hw][row * LDV + 48 + lm] = f2bf(e3 * inv);
        }
        __syncthreads();

        // z_h = P @ V_h : wave wg -> m-tile wg, n-tiles 0..1 (head-dim halves), K=64
        floatx4 zacc[2];
        zacc[0] = (floatx4){0.f, 0.f, 0.f, 0.f};
        zacc[1] = (floatx4){0.f, 0.f, 0.f, 0.f};
        #pragma unroll
        for (int k0 = 0; k0 < 64; k0 += 32) {
            short8 ap = *(const short8*)(&sP[hw][(wg * 16 + lm) * LDV + k0 + quad * 8]);
            #pragma unroll
            for (int n = 0; n < 2; n++) {
                short8 bvf = *(const short8*)(&sVT[(hc + n * 16 + lm) * LDV + k0 + quad * 8]);
                zacc[n] = __builtin_amdgcn_mfma_f32_16x16x32_bf16(ap, bvf, zacc[n], 0, 0, 0);
            }
        }
        // z_h overwrites the (now dead) Q columns of head h, rows this wave owns
        #pragma unroll
        for (int n = 0; n < 2; n++)
            #pragma unroll
            for (int r = 0; r < 4; r++) {
                int row = wg * 16 + quad * 4 + r;
                sQ[row * LDA + hc + n * 16 + lm] = f2bf(zacc[n][r]);
            }
        __syncthreads();
    }

    // ---- Phase 3: f = relu(Z @ W1 + b1 + x); dot with W2; sigmoid ----
    float dot = 0.f;
    {
        floatx4 acc[4][2];
        #pragma unroll
        for (int mt = 0; mt < 4; mt++)
            #pragma unroll
            for (int n = 0; n < 2; n++)
                acc[mt][n] = (floatx4){0.f, 0.f, 0.f, 0.f};
        for (int k0 = 0; k0 < DIM; k0 += 32) {
            short8 a[4], b[2];
            #pragma unroll
            for (int mt = 0; mt < 4; mt++)
                a[mt] = *(const short8*)(&sQ[(mt * 16 + lm) * LDA + k0 + quad * 8]);
            #pragma unroll
            for (int n = 0; n < 2; n++)
                b[n] = *(const short8*)(&w1T[((nbase + n) * 16 + lm) * DIM + k0 + quad * 8]);
            #pragma unroll
            for (int mt = 0; mt < 4; mt++)
                #pragma unroll
                for (int n = 0; n < 2; n++)
                    acc[mt][n] = __builtin_amdgcn_mfma_f32_16x16x32_bf16(
                        a[mt], b[n], acc[mt][n], 0, 0, 0);
        }
        #pragma unroll
        for (int n = 0; n < 2; n++) {
            int ncol = (nbase + n) * 16 + lm;
            float b1v = b1[ncol];
            #pragma unroll
            for (int mt = 0; mt < 4; mt++)
                #pragma unroll
                for (int r = 0; r < 4; r++) {
                    int row = mt * 16 + quad * 4 + r;
                    float f = acc[mt][n][r] + b1v + bf2f(sX[row * LDA + ncol]);
                    f = fmaxf(f, 0.f);
                    dot += f * w2[row * DIM + ncol];
                }
        }
    }
    // block reduction -> sigmoid -> f32 out
    #pragma unroll
    for (int off = 1; off < 64; off <<= 1)
        dot += __shfl_xor(dot, off, 64);
    if (lane == 0) sRed[wave] = dot;
    __syncthreads();
    if (tid == 0) {
        float t = 0.f;
        #pragma unroll
        for (int w = 0; w < 8; w++) t += sRed[w];
        t += b2[0];
        out[blockIdx.x] = 1.0f / (1.0f + __expf(-t));
    }
}

extern "C" void kernel_launch(void* const* d_in, const int* in_sizes, int n_in,
                              void* d_out, int out_size, void* d_ws, size_t ws_size,
                              hipStream_t stream) {
    const float* x  = (const float*)d_in[0];
    const float* Wq = (const float*)d_in[1];
    const float* bq = (const float*)d_in[2];
    const float* Wk = (const float*)d_in[3];
    const float* bk = (const float*)d_in[4];
    const float* Wv = (const float*)d_in[5];
    const float* bv = (const float*)d_in[6];
    const float* W1 = (const float*)d_in[7];
    const float* b1 = (const float*)d_in[8];
    const float* W2 = (const float*)d_in[9];
    const float* b2 = (const float*)d_in[10];
    ushort* ws = (ushort*)d_ws;

    transpose4<<<dim3(256, 4), 256, 0, stream>>>(Wq, Wk, Wv, W1, ws);
    autoint_kernel<<<NBATCH, 512, 0, stream>>>(
        x, ws, ws + 65536, ws + 131072, ws + 196608,
        bq, bk, bv, b1, W2, b2, (float*)d_out);
}